// Round 1
// baseline (183.662 us; speedup 1.0000x reference)
//
#include <hip/hip_runtime.h>
#include <hip/hip_bf16.h>

// GQA causal attention fwd: B=1, H=16, HKV=4, S=2048, D=128, fp32 in/out.
// Flash-style: QBLK=64 (4 waves x 16 rows), KVBLK=64, bf16 MFMA 16x16x32.

#define NH   16
#define NHKV 4
#define SEQ  2048
#define DIM  128
#define QBLK 64
#define KVBLK 64

typedef __attribute__((ext_vector_type(8))) short bf16x8_t;
typedef __attribute__((ext_vector_type(4))) float f32x4_t;

__device__ inline ushort f2bf(float f) {
    // round-to-nearest-even bf16 (finite inputs only)
    uint x = __float_as_uint(f);
    uint r = (x + 0x7fffu + ((x >> 16) & 1u)) >> 16;
    return (ushort)r;
}

extern "C" __global__ __launch_bounds__(256)
void attn_fwd(const float* __restrict__ Q, const float* __restrict__ K,
              const float* __restrict__ V, float* __restrict__ O)
{
    const int h   = blockIdx.y;
    const int kvh = h >> 2;                         // gqa_group_size = 4
    const int qt  = (SEQ / QBLK - 1) - blockIdx.x;  // longest blocks first
    const int q0  = qt * QBLK;
    const int tid  = threadIdx.x;
    const int w    = tid >> 6;
    const int lane = tid & 63;
    const int g    = lane >> 4;   // 0..3
    const int r    = lane & 15;   // 0..15

    // K tile bf16 [64][128], swizzled: byte = (row*256 + d*2) ^ ((row&7)<<4)
    __shared__ ushort Ksh[KVBLK * DIM];
    // V tile transposed bf16 [128][64], swizzled: byte = (d*128 + kv*2) ^ ((d&7)<<4)
    __shared__ ushort Vtsh[DIM * KVBLK];
    // P per-wave bf16 [16][64], swizzled: byte = (row*128 + col*2) ^ ((row&7)<<4)
    __shared__ ushort Psh[4 * 16 * 64];

    // fold 1/sqrt(D) and log2(e) into Q so softmax uses exp2 directly
    const float qscale = 0.08838834764831845f * 1.4426950408889634f;

    // ---- Q fragments in registers (A-frag: row = lane&15, k = g*8 + i) ----
    bf16x8_t qf[4];
    {
        const int qrow = q0 + w * 16 + r;
        const float* qp = Q + ((size_t)h * SEQ + qrow) * DIM + g * 8;
#pragma unroll
        for (int kb = 0; kb < 4; ++kb) {
            float4 f0 = *(const float4*)(qp + kb * 32);
            float4 f1 = *(const float4*)(qp + kb * 32 + 4);
            bf16x8_t a;
            a[0] = (short)f2bf(f0.x * qscale); a[1] = (short)f2bf(f0.y * qscale);
            a[2] = (short)f2bf(f0.z * qscale); a[3] = (short)f2bf(f0.w * qscale);
            a[4] = (short)f2bf(f1.x * qscale); a[5] = (short)f2bf(f1.y * qscale);
            a[6] = (short)f2bf(f1.z * qscale); a[7] = (short)f2bf(f1.w * qscale);
            qf[kb] = a;
        }
    }

    f32x4_t o_acc[8];
#pragma unroll
    for (int i = 0; i < 8; ++i) { f32x4_t z = {0.f, 0.f, 0.f, 0.f}; o_acc[i] = z; }
    float m_r[4], l_r[4];
#pragma unroll
    for (int pr = 0; pr < 4; ++pr) { m_r[pr] = -1e30f; l_r[pr] = 0.f; }

    const int nt = qt + 1;
    for (int t = 0; t < nt; ++t) {
        const int j0 = t * KVBLK;
        __syncthreads();   // previous tile's LDS reads done before overwrite

        // ---- stage K tile: [64][128] fp32 -> swizzled bf16 LDS ----
        {
            const float* kb_ = K + ((size_t)kvh * SEQ + j0) * DIM;
#pragma unroll
            for (int it = 0; it < 8; ++it) {
                int cid = tid + it * 256;       // float4 chunk 0..2047
                int row = cid >> 5;             // 32 chunks per row
                int d   = (cid & 31) * 4;
                float4 f = *(const float4*)(kb_ + row * DIM + d);
                uint lo = (uint)f2bf(f.x) | ((uint)f2bf(f.y) << 16);
                uint hi = (uint)f2bf(f.z) | ((uint)f2bf(f.w) << 16);
                uint byte = ((uint)(row * 256 + d * 2)) ^ ((uint)(row & 7) << 4);
                *(uint2*)((char*)Ksh + byte) = make_uint2(lo, hi);
            }
            // ---- stage V transposed: Vt[d][kv], 4 kv packed per 8B write ----
            const float* vb_ = V + ((size_t)kvh * SEQ + j0) * DIM;
#pragma unroll
            for (int it = 0; it < 8; ++it) {
                int pid = tid + it * 256;       // 0..2047
                int d   = pid & 127;
                int kv  = (pid >> 7) * 4;       // 0..60
                float v0 = vb_[(kv + 0) * DIM + d];
                float v1 = vb_[(kv + 1) * DIM + d];
                float v2 = vb_[(kv + 2) * DIM + d];
                float v3 = vb_[(kv + 3) * DIM + d];
                uint lo = (uint)f2bf(v0) | ((uint)f2bf(v1) << 16);
                uint hi = (uint)f2bf(v2) | ((uint)f2bf(v3) << 16);
                uint byte = ((uint)(d * 128 + kv * 2)) ^ ((uint)(d & 7) << 4);
                *(uint2*)((char*)Vtsh + byte) = make_uint2(lo, hi);
            }
        }
        __syncthreads();   // staging complete

        // ---- QK^T: S[16 q][64 kv], 16 MFMAs ----
        f32x4_t sacc[4];
#pragma unroll
        for (int n = 0; n < 4; ++n) { f32x4_t z = {0.f, 0.f, 0.f, 0.f}; sacc[n] = z; }
#pragma unroll
        for (int n = 0; n < 4; ++n) {
            const int krow = n * 16 + r;       // kv row in tile (B col = lane&15)
            const uint sw = ((uint)(krow & 7)) << 4;
#pragma unroll
            for (int kb = 0; kb < 4; ++kb) {
                uint byte = ((uint)(krow * 256 + (kb * 32 + g * 8) * 2)) ^ sw;
                bf16x8_t bfrag = *(bf16x8_t*)((char*)Ksh + byte);
                sacc[n] = __builtin_amdgcn_mfma_f32_16x16x32_bf16(qf[kb], bfrag, sacc[n], 0, 0, 0);
            }
        }

        // ---- causal mask (only the diagonal tile: j0 == q0) ----
        if (t == nt - 1) {
#pragma unroll
            for (int n = 0; n < 4; ++n)
#pragma unroll
                for (int pr = 0; pr < 4; ++pr) {
                    int limit = w * 16 + g * 4 + pr;   // local q row
                    int col   = n * 16 + r;
                    if (col > limit) sacc[n][pr] = -1e30f;
                }
        }

        // ---- online softmax (row spread over 16 lanes, shfl_xor reduce) ----
        float pm[4];
#pragma unroll
        for (int pr = 0; pr < 4; ++pr) {
            float mx = fmaxf(fmaxf(sacc[0][pr], sacc[1][pr]),
                             fmaxf(sacc[2][pr], sacc[3][pr]));
#pragma unroll
            for (int mask = 1; mask < 16; mask <<= 1)
                mx = fmaxf(mx, __shfl_xor(mx, mask, 64));
            pm[pr] = mx;
        }
        float alpha[4];
#pragma unroll
        for (int pr = 0; pr < 4; ++pr) {
            float mnew = fmaxf(m_r[pr], pm[pr]);
            alpha[pr] = __builtin_exp2f(m_r[pr] - mnew);
            m_r[pr] = mnew;
        }
        float ps[4] = {0.f, 0.f, 0.f, 0.f};
#pragma unroll
        for (int n = 0; n < 4; ++n)
#pragma unroll
            for (int pr = 0; pr < 4; ++pr) {
                float p = __builtin_exp2f(sacc[n][pr] - m_r[pr]);
                sacc[n][pr] = p;
                ps[pr] += p;
            }
#pragma unroll
        for (int pr = 0; pr < 4; ++pr) {
            float s = ps[pr];
#pragma unroll
            for (int mask = 1; mask < 16; mask <<= 1)
                s += __shfl_xor(s, mask, 64);
            l_r[pr] = l_r[pr] * alpha[pr] + s;
        }
#pragma unroll
        for (int nd = 0; nd < 8; ++nd)
#pragma unroll
            for (int pr = 0; pr < 4; ++pr)
                o_acc[nd][pr] *= alpha[pr];

        // ---- P: C-layout -> A-frag layout via per-wave LDS round trip ----
        char* pbase = (char*)Psh + w * 2048;
#pragma unroll
        for (int n = 0; n < 4; ++n)
#pragma unroll
            for (int pr = 0; pr < 4; ++pr) {
                int row = g * 4 + pr;
                int col = n * 16 + r;
                uint byte = ((uint)(row * 128 + col * 2)) ^ ((uint)(row & 7) << 4);
                *(ushort*)(pbase + byte) = f2bf(sacc[n][pr]);
            }
        asm volatile("s_waitcnt lgkmcnt(0)" ::: "memory");

        // ---- PV: O[16 q][128 d] += P * V, 16 MFMAs ----
#pragma unroll
        for (int kb = 0; kb < 2; ++kb) {
            uint pbyte = ((uint)(r * 128 + (kb * 32 + g * 8) * 2)) ^ ((uint)(r & 7) << 4);
            bf16x8_t pa = *(bf16x8_t*)(pbase + pbyte);
#pragma unroll
            for (int nd = 0; nd < 8; ++nd) {
                int d = nd * 16 + r;
                uint vbyte = ((uint)(d * 128 + (kb * 32 + g * 8) * 2)) ^ ((uint)(d & 7) << 4);
                bf16x8_t vb = *(bf16x8_t*)((char*)Vtsh + vbyte);
                o_acc[nd] = __builtin_amdgcn_mfma_f32_16x16x32_bf16(pa, vb, o_acc[nd], 0, 0, 0);
            }
        }
    }

    // ---- epilogue: O = acc / l ----
#pragma unroll
    for (int pr = 0; pr < 4; ++pr) {
        float inv = 1.0f / l_r[pr];
        int qrow = q0 + w * 16 + g * 4 + pr;
        float* op = O + ((size_t)h * SEQ + qrow) * DIM;
#pragma unroll
        for (int nd = 0; nd < 8; ++nd)
            op[nd * 16 + r] = o_acc[nd][pr] * inv;
    }
}

extern "C" void kernel_launch(void* const* d_in, const int* in_sizes, int n_in,
                              void* d_out, int out_size, void* d_ws, size_t ws_size,
                              hipStream_t stream) {
    const float* Q = (const float*)d_in[0];
    const float* K = (const float*)d_in[1];
    const float* V = (const float*)d_in[2];
    float* O = (float*)d_out;
    dim3 grid(SEQ / QBLK, NH);
    attn_fwd<<<grid, 256, 0, stream>>>(Q, K, V, O);
}

// Round 2
// 165.991 us; speedup vs baseline: 1.1065x; 1.1065x over previous
//
#include <hip/hip_runtime.h>
#include <hip/hip_bf16.h>

// GQA causal attention fwd: B=1, H=16, HKV=4, S=2048, D=128, fp32 in/out.
// Round 2: prep-pass pre-converts K/V to bf16 swizzled LDS tile images in d_ws;
// main loop stages via global_load_lds (16B), double-buffered, 1 barrier/tile.

#define NH    16
#define NHKV  4
#define SEQ   2048
#define DIM   128
#define QBLK  64
#define KVBLK 64
#define NT    (SEQ / KVBLK)   // 32 kv tiles

typedef __attribute__((ext_vector_type(8))) short bf16x8_t;
typedef __attribute__((ext_vector_type(4))) float f32x4_t;

__device__ inline ushort f2bf(float f) {
    uint x = __float_as_uint(f);
    uint r = (x + 0x7fffu + ((x >> 16) & 1u)) >> 16;
    return (ushort)r;
}

#define GLOAD_LDS16(gsrc, ldst) \
    __builtin_amdgcn_global_load_lds( \
        (const __attribute__((address_space(1))) void*)(gsrc), \
        (__attribute__((address_space(3))) void*)(ldst), 16, 0, 0)

// ---- prep: K -> bf16 swizzled [kvh][tile][row*256 + d*2 ^ swz] images,
//            V -> bf16 transposed swizzled [kvh][tile][d*128 + kv*2 ^ swz] images
extern "C" __global__ __launch_bounds__(256)
void prep_kv(const float* __restrict__ K, const float* __restrict__ V,
             ushort* __restrict__ Kpre, ushort* __restrict__ Vpre)
{
    int gid = blockIdx.x * 256 + threadIdx.x;
    if (blockIdx.x < 1024) {
        // K: thread = (kvh, s, dq/4). 4*2048*32 = 262144 threads
        int kvh = gid >> 16; int rem = gid & 65535;
        int s = rem >> 5; int dq = (rem & 31) << 2;
        float4 f = *(const float4*)(K + ((size_t)(kvh * SEQ + s)) * DIM + dq);
        uint lo = (uint)f2bf(f.x) | ((uint)f2bf(f.y) << 16);
        uint hi = (uint)f2bf(f.z) | ((uint)f2bf(f.w) << 16);
        int tile = s >> 6, row = s & 63;
        uint byte = ((uint)(row * 256 + dq * 2)) ^ ((uint)(row & 7) << 4);
        *(uint2*)((char*)Kpre + (((size_t)(kvh * NT + tile)) << 14) + byte) =
            make_uint2(lo, hi);
    } else {
        // V: thread = (kvh, tile, kv/4, d). coalesced reads over d.
        int g2 = gid - 1024 * 256;
        int kvh = g2 >> 16; int rem = g2 & 65535;
        int d = rem & 127; int t2 = rem >> 7;
        int tile = t2 >> 4; int kv = (t2 & 15) << 2;
        const float* b = V + ((size_t)(kvh * SEQ + tile * 64 + kv)) * DIM + d;
        uint lo = (uint)f2bf(b[0])       | ((uint)f2bf(b[DIM]) << 16);
        uint hi = (uint)f2bf(b[2 * DIM]) | ((uint)f2bf(b[3 * DIM]) << 16);
        uint byte = ((uint)(d * 128 + kv * 2)) ^ ((uint)(d & 7) << 4);
        *(uint2*)((char*)Vpre + (((size_t)(kvh * NT + tile)) << 14) + byte) =
            make_uint2(lo, hi);
    }
}

extern "C" __global__ __launch_bounds__(256)
void attn_fwd(const float* __restrict__ Q, const ushort* __restrict__ Kpre,
              const ushort* __restrict__ Vpre, float* __restrict__ O)
{
    const int h   = blockIdx.y;
    const int kvh = h >> 2;                         // gqa_group_size = 4
    const int qt  = (SEQ / QBLK - 1) - blockIdx.x;  // longest blocks first
    const int q0  = qt * QBLK;
    const int tid  = threadIdx.x;
    const int w    = tid >> 6;
    const int lane = tid & 63;
    const int g    = lane >> 4;   // 0..3
    const int r    = lane & 15;   // 0..15

    // double-buffered K [64][128] and Vt [128][64] bf16 swizzled tile images
    __shared__ ushort Ksh[2][KVBLK * DIM];
    __shared__ ushort Vtsh[2][DIM * KVBLK];
    // P per-wave bf16 [16][64], swizzled: byte = (row*128 + col*2) ^ ((row&7)<<4)
    __shared__ ushort Psh[4 * 16 * 64];

    const float qscale = 0.08838834764831845f * 1.4426950408889634f; // 1/sqrt(D)*log2e

    // ---- Q fragments (A-frag: row = lane&15, k = g*8 + i), pre-scaled ----
    bf16x8_t qf[4];
    {
        const int qrow = q0 + w * 16 + r;
        const float* qp = Q + ((size_t)h * SEQ + qrow) * DIM + g * 8;
#pragma unroll
        for (int kb = 0; kb < 4; ++kb) {
            float4 f0 = *(const float4*)(qp + kb * 32);
            float4 f1 = *(const float4*)(qp + kb * 32 + 4);
            bf16x8_t a;
            a[0] = (short)f2bf(f0.x * qscale); a[1] = (short)f2bf(f0.y * qscale);
            a[2] = (short)f2bf(f0.z * qscale); a[3] = (short)f2bf(f0.w * qscale);
            a[4] = (short)f2bf(f1.x * qscale); a[5] = (short)f2bf(f1.y * qscale);
            a[6] = (short)f2bf(f1.z * qscale); a[7] = (short)f2bf(f1.w * qscale);
            qf[kb] = a;
        }
    }

    f32x4_t o_acc[8];
#pragma unroll
    for (int i = 0; i < 8; ++i) { f32x4_t z = {0.f, 0.f, 0.f, 0.f}; o_acc[i] = z; }
    float m_r[4], l_r[4];
#pragma unroll
    for (int pr = 0; pr < 4; ++pr) { m_r[pr] = -1e30f; l_r[pr] = 0.f; }

    const size_t kvbase = (size_t)kvh * NT;

    // stage one 16KB K image + 16KB Vt image into buffer b (linear copy)
    auto stage = [&](int b, int t) {
        const char* kg = (const char*)Kpre + ((kvbase + t) << 14) + tid * 16;
        const char* vg = (const char*)Vpre + ((kvbase + t) << 14) + tid * 16;
        char* kl = (char*)&Ksh[b][0] + tid * 16;
        char* vl = (char*)&Vtsh[b][0] + tid * 16;
#pragma unroll
        for (int c = 0; c < 4; ++c) {
            GLOAD_LDS16(kg + c * 4096, kl + c * 4096);
            GLOAD_LDS16(vg + c * 4096, vl + c * 4096);
        }
    };

    const int nt = qt + 1;
    stage(0, 0);
    __syncthreads();           // implicit vmcnt(0) drains the stage
    int buf = 0;

    for (int t = 0; t < nt; ++t) {
        if (t + 1 < nt) stage(buf ^ 1, t + 1);   // prefetch overlaps compute

        // ---- QK^T: S[16 q][64 kv], 16 MFMAs ----
        f32x4_t sacc[4];
#pragma unroll
        for (int n = 0; n < 4; ++n) { f32x4_t z = {0.f, 0.f, 0.f, 0.f}; sacc[n] = z; }
        __builtin_amdgcn_s_setprio(1);
#pragma unroll
        for (int n = 0; n < 4; ++n) {
            const int krow = n * 16 + r;       // kv row (B col = lane&15)
            const uint sw = ((uint)(krow & 7)) << 4;
#pragma unroll
            for (int kb = 0; kb < 4; ++kb) {
                uint byte = ((uint)(krow * 256 + (kb * 32 + g * 8) * 2)) ^ sw;
                bf16x8_t bfrag = *(bf16x8_t*)((char*)&Ksh[buf][0] + byte);
                sacc[n] = __builtin_amdgcn_mfma_f32_16x16x32_bf16(qf[kb], bfrag, sacc[n], 0, 0, 0);
            }
        }
        __builtin_amdgcn_s_setprio(0);

        // ---- causal mask (diagonal tile only) ----
        if (t == nt - 1) {
#pragma unroll
            for (int n = 0; n < 4; ++n)
#pragma unroll
                for (int pr = 0; pr < 4; ++pr) {
                    int limit = w * 16 + g * 4 + pr;
                    int col   = n * 16 + r;
                    if (col > limit) sacc[n][pr] = -1e30f;
                }
        }

        // ---- online softmax (rows spread over 16 lanes, shfl_xor reduce) ----
        float pm[4];
#pragma unroll
        for (int pr = 0; pr < 4; ++pr) {
            float mx = fmaxf(fmaxf(sacc[0][pr], sacc[1][pr]),
                             fmaxf(sacc[2][pr], sacc[3][pr]));
#pragma unroll
            for (int mask = 1; mask < 16; mask <<= 1)
                mx = fmaxf(mx, __shfl_xor(mx, mask, 64));
            pm[pr] = mx;
        }
        float alpha[4];
#pragma unroll
        for (int pr = 0; pr < 4; ++pr) {
            float mnew = fmaxf(m_r[pr], pm[pr]);
            alpha[pr] = __builtin_exp2f(m_r[pr] - mnew);
            m_r[pr] = mnew;
        }
        float ps[4] = {0.f, 0.f, 0.f, 0.f};
#pragma unroll
        for (int n = 0; n < 4; ++n)
#pragma unroll
            for (int pr = 0; pr < 4; ++pr) {
                float p = __builtin_exp2f(sacc[n][pr] - m_r[pr]);
                sacc[n][pr] = p;
                ps[pr] += p;
            }
#pragma unroll
        for (int pr = 0; pr < 4; ++pr) {
            float s = ps[pr];
#pragma unroll
            for (int mask = 1; mask < 16; mask <<= 1)
                s += __shfl_xor(s, mask, 64);
            l_r[pr] = l_r[pr] * alpha[pr] + s;
        }
#pragma unroll
        for (int nd = 0; nd < 8; ++nd)
#pragma unroll
            for (int pr = 0; pr < 4; ++pr)
                o_acc[nd][pr] *= alpha[pr];

        // ---- P: C-layout -> A-frag layout via per-wave LDS round trip ----
        char* pbase = (char*)Psh + w * 2048;
#pragma unroll
        for (int n = 0; n < 4; ++n)
#pragma unroll
            for (int pr = 0; pr < 4; ++pr) {
                int row = g * 4 + pr;
                int col = n * 16 + r;
                uint byte = ((uint)(row * 128 + col * 2)) ^ ((uint)(row & 7) << 4);
                *(ushort*)(pbase + byte) = f2bf(sacc[n][pr]);
            }
        asm volatile("s_waitcnt lgkmcnt(0)" ::: "memory");

        // ---- PV: O[16 q][128 d] += P * V, 16 MFMAs ----
        __builtin_amdgcn_s_setprio(1);
#pragma unroll
        for (int kb = 0; kb < 2; ++kb) {
            uint pbyte = ((uint)(r * 128 + (kb * 32 + g * 8) * 2)) ^ ((uint)(r & 7) << 4);
            bf16x8_t pa = *(bf16x8_t*)(pbase + pbyte);
#pragma unroll
            for (int nd = 0; nd < 8; ++nd) {
                int d = nd * 16 + r;
                uint vbyte = ((uint)(d * 128 + (kb * 32 + g * 8) * 2)) ^ ((uint)(d & 7) << 4);
                bf16x8_t vb = *(bf16x8_t*)((char*)&Vtsh[buf][0] + vbyte);
                o_acc[nd] = __builtin_amdgcn_mfma_f32_16x16x32_bf16(pa, vb, o_acc[nd], 0, 0, 0);
            }
        }
        __builtin_amdgcn_s_setprio(0);

        __syncthreads();   // drains prefetch (vmcnt) + frees buf for next stage
        buf ^= 1;
    }

    // ---- epilogue: O = acc / l ----
#pragma unroll
    for (int pr = 0; pr < 4; ++pr) {
        float inv = 1.0f / l_r[pr];
        int qrow = q0 + w * 16 + g * 4 + pr;
        float* op = O + ((size_t)h * SEQ + qrow) * DIM;
#pragma unroll
        for (int nd = 0; nd < 8; ++nd)
            op[nd * 16 + r] = o_acc[nd][pr] * inv;
    }
}

extern "C" void kernel_launch(void* const* d_in, const int* in_sizes, int n_in,
                              void* d_out, int out_size, void* d_ws, size_t ws_size,
                              hipStream_t stream) {
    const float* Q = (const float*)d_in[0];
    const float* K = (const float*)d_in[1];
    const float* V = (const float*)d_in[2];
    float* O = (float*)d_out;
    ushort* Kpre = (ushort*)d_ws;                          // 2 MB
    ushort* Vpre = (ushort*)((char*)d_ws + (2u << 20));    // 2 MB
    prep_kv<<<2048, 256, 0, stream>>>(K, V, Kpre, Vpre);
    dim3 grid(SEQ / QBLK, NH);
    attn_fwd<<<grid, 256, 0, stream>>>(Q, Kpre, Vpre, O);
}